// Round 5
// baseline (766.032 us; speedup 1.0000x reference)
//
#include <hip/hip_runtime.h>
#include <hip/hip_bf16.h>
#include <hip/hip_fp16.h>
#include <cstdint>

#define B_ 16
#define N_ 2048
#define D_ 1024

typedef __attribute__((ext_vector_type(4))) float f32x4;
typedef __attribute__((ext_vector_type(16))) float f32x16;
typedef __attribute__((ext_vector_type(8))) short s16x8;

typedef __attribute__((address_space(1))) const void* gas_ptr;
typedef __attribute__((address_space(3))) void* las_ptr;

__device__ __forceinline__ void gload16(const void* g, void* l)
{
    __builtin_amdgcn_global_load_lds((gas_ptr)(uintptr_t)g, (las_ptr)(uintptr_t)l, 16, 0, 0);
}

__device__ __forceinline__ ushort f2bf(float f)
{
    union { __hip_bfloat16 h; ushort u; } c;
    c.h = __float2bfloat16(f);
    return c.u;
}
__device__ __forceinline__ float bf2f(ushort u)
{
    union { __hip_bfloat16 h; ushort u; } c;
    c.u = u;
    return __bfloat162float(c.h);
}

// ---------------------------------------------------------------------------
// fp32 -> bf16 convert (vectorized, grid-stride)
// ---------------------------------------------------------------------------
__global__ __launch_bounds__(256)
void cvt_bf16(const float* __restrict__ in, ushort* __restrict__ out, long n)
{
    long i = ((long)blockIdx.x * 256 + threadIdx.x) * 8;
    const long stride = (long)gridDim.x * 256 * 8;
    for (; i < n; i += stride) {
        f32x4 a = *(const f32x4*)(in + i);
        f32x4 b = *(const f32x4*)(in + i + 4);
        s16x8 o;
#pragma unroll
        for (int j = 0; j < 4; ++j) { o[j] = (short)f2bf(a[j]); o[4 + j] = (short)f2bf(b[j]); }
        *(s16x8*)(out + i) = o;
    }
}

// ---------------------------------------------------------------------------
// weights: bf16 convert + fold W1+W2+W3, b1+b2+b3
// ---------------------------------------------------------------------------
__global__ __launch_bounds__(256)
void prep_w(const float* __restrict__ Wq, const float* __restrict__ Wk, const float* __restrict__ Wv,
            const float* __restrict__ W1, const float* __restrict__ W2, const float* __restrict__ W3,
            const float* __restrict__ b1, const float* __restrict__ b2, const float* __restrict__ b3,
            ushort* __restrict__ wq, ushort* __restrict__ wk, ushort* __restrict__ wv,
            ushort* __restrict__ wsum, float* __restrict__ bsum)
{
    const long i = ((long)blockIdx.x * 256 + threadIdx.x) * 4;
    if (i < (long)D_ * D_) {
#pragma unroll
        for (int j = 0; j < 4; ++j) {
            wq[i + j] = f2bf(Wq[i + j]);
            wk[i + j] = f2bf(Wk[i + j]);
            wv[i + j] = f2bf(Wv[i + j]);
            wsum[i + j] = f2bf(W1[i + j] + W2[i + j] + W3[i + j]);
        }
        if (i < D_) {
#pragma unroll
            for (int j = 0; j < 4; ++j) bsum[i + j] = b1[i + j] + b2[i + j] + b3[i + j];
        }
    }
}

// ---------------------------------------------------------------------------
// 256x256 8-phase bf16 GEMM, 32x32x16 MFMA core:
//   C[m,n] = sum_k A[m,k]*B[n,k] (+epilogue), both operands row-major [rows,K]
//   BK=64, 8 waves (2M x 4N), per-wave 128x64 output = 4x2 frags of 32x32,
//   4 ksteps of 16. LDS 128KB dbuf, st_16x32 swizzle; linear gload_lds dest +
//   inverse-swizzled global source + swizzled ds_read (rule #21).
//   Round-1 schedule (best measured): per phase {ds_reads, 1 half-tile stage,
//   barrier, lgkmcnt(0), 8 MFMA (setprio), barrier}; vmcnt(2) at tile end
//   (stage rotation: halves 1-3 of t+1 in ph0-2, half 0 of t+2 in ph3).
// EPI: 0 = +bias[n] -> bf16 | 1 = fp16 | 2 = bf16 | 3 = sigmoid gate -> fp32
//      4 = +bias[m] (row bias) -> bf16
// ---------------------------------------------------------------------------
template<int EPI>
__global__ __launch_bounds__(512, 2)
void gemm256(const ushort* __restrict__ A, const ushort* __restrict__ Bw,
             void* __restrict__ Out, const float* __restrict__ bias,
             int Nn, int K, int NT,
             long sA, long sB, long sO,
             const ushort* __restrict__ outb, const float* __restrict__ x1r,
             const float* __restrict__ gamma)
{
    __shared__ ushort lds[65536];           // 128 KB
    const int tid = threadIdx.x;
    const int l = tid & 63;
    const int w = tid >> 6;
    const int wm = w >> 2, wn = w & 3;
    const int rA = l & 31;                       // row within 32-row frag
    // physical 16B slot for kstep ks: ((ks&1)^row_bit3)<<1 | kgroup, row_bit3 = l&8
    const int slotbase = (((l >> 3) & 1) << 1) | ((l >> 5) & 1);

    // bijective XCD-aware block swizzle (all grids are multiples of 8)
    const int gx = gridDim.x, gy = gridDim.y;
    const int nwg = gx * gy * (int)gridDim.z;
    const int orig = ((int)blockIdx.z * gy + blockIdx.y) * gx + blockIdx.x;
    const int swzb = (orig & 7) * (nwg >> 3) + (orig >> 3);
    const int gxy = gx * gy;
    const int bz = swzb / gxy;
    const int rem = swzb - bz * gxy;
    const int by = rem / gx;
    const int bx = rem - by * gx;
    const int m0 = by * 256, n0 = bx * 256;

    const ushort* Ab = A + (long)bz * sA;
    const ushort* Bb = Bw + (long)bz * sB;

    // stage source decode: linear LDS chunk c -> (row, col) via inverse swizzle
    int srow[2], scol[2];
#pragma unroll
    for (int i = 0; i < 2; ++i) {
        const int L = (i * 512 + tid) * 16;
        const int P = L ^ (((L >> 9) & 1) << 5);
        srow[i] = (P >> 6) & 127;
        scol[i] = ((P >> 13) << 5) | ((P & 63) >> 1);
    }
    const int sdst = w * 512;   // wave-uniform LDS chunk base (ushorts), i adds 4096

    f32x16 acc[4][2];
#pragma unroll
    for (int i = 0; i < 4; ++i)
#pragma unroll
        for (int j = 0; j < 2; ++j)
#pragma unroll
            for (int r = 0; r < 16; ++r) acc[i][j][r] = 0.f;
    s16x8 a[2][4], b[2][4];

#define STAGEH(pl, t)                                                                     \
    if ((t) < NT) {                                                                       \
        const int rb2 = (t) & 1;                                                          \
        const long kk = (long)(t) << 6;                                                   \
        _Pragma("unroll")                                                                 \
        for (int i = 0; i < 2; ++i) {                                                     \
            if ((pl) < 2)                                                                 \
                gload16(Ab + (long)(m0 + (pl) * 128 + srow[i]) * K + kk + scol[i],        \
                        &lds[rb2 * 16384 + (pl) * 8192 + sdst + i * 4096]);               \
            else                                                                          \
                gload16(Bb + (long)(n0 + ((pl) - 2) * 128 + srow[i]) * K + kk + scol[i],  \
                        &lds[32768 + rb2 * 16384 + ((pl) - 2) * 8192 + sdst + i * 4096]); \
        }                                                                                 \
    }

// A-frag pair h (frags 2h, 2h+1): rows (2h+f2)*32 + rA of wave's 128-row half
#define LDA_(h)                                                                            \
    _Pragma("unroll") for (int f2 = 0; f2 < 2; ++f2)                                       \
    _Pragma("unroll") for (int ks = 0; ks < 4; ++ks)                                       \
        a[f2][ks] = *(const s16x8*)&lds[rbase_a + (ks >> 1) * 4096 +                       \
            (((h) * 2 + f2) * 32 + rA) * 32 + ((slotbase ^ ((ks & 1) << 1)) << 3)];

// B-frag c: rows (wn&1)*64 + c*32 + rA of the B half-panel
#define LDB_(c)                                                                            \
    _Pragma("unroll") for (int ks = 0; ks < 4; ++ks)                                       \
        b[c][ks] = *(const s16x8*)&lds[rbase_b + (ks >> 1) * 4096 +                        \
            ((wn & 1) * 64 + (c) * 32 + rA) * 32 + ((slotbase ^ ((ks & 1) << 1)) << 3)];

#define MM_(h, c)                                                                          \
    __builtin_amdgcn_s_setprio(1);                                                         \
    _Pragma("unroll") for (int f2 = 0; f2 < 2; ++f2)                                       \
    _Pragma("unroll") for (int ks = 0; ks < 4; ++ks)                                       \
        acc[(h) * 2 + f2][c] = __builtin_amdgcn_mfma_f32_32x32x16_bf16(                    \
            a[f2][ks], b[c][ks], acc[(h) * 2 + f2][c], 0, 0, 0);                           \
    __builtin_amdgcn_s_setprio(0);

#define BARR __builtin_amdgcn_s_barrier()
#define LGKM0 do { asm volatile("s_waitcnt lgkmcnt(0)" ::: "memory"); \
                   __builtin_amdgcn_sched_barrier(0); } while (0)

#define KGROUP(tt, VMSTR) {                                          \
    const int rb = (tt) & 1;                                         \
    const int rbase_a = rb * 16384 + wm * 8192;                      \
    const int rbase_b = 32768 + rb * 16384 + (wn >> 1) * 8192;       \
    /* ph0 */                                                        \
    LDB_(0); LDA_(0);                                                \
    STAGEH(1, (tt) + 1);                                             \
    BARR; LGKM0; MM_(0, 0); BARR;                                    \
    /* ph1 */                                                        \
    LDB_(1);                                                         \
    STAGEH(2, (tt) + 1);                                             \
    BARR; LGKM0; MM_(0, 1); BARR;                                    \
    /* ph2 */                                                        \
    LDA_(1);                                                         \
    STAGEH(3, (tt) + 1);                                             \
    BARR; LGKM0; MM_(1, 0); BARR;                                    \
    /* ph3: full frag reuse; stage next-next tile's A-half0 after MFMA */ \
    MM_(1, 1);                                                       \
    STAGEH(0, (tt) + 2);                                             \
    asm volatile("s_waitcnt " VMSTR ::: "memory");                   \
    BARR; }

    // prologue: tile0 fully + half0 of tile1 in flight
    STAGEH(0, 0); STAGEH(1, 0); STAGEH(2, 0); STAGEH(3, 0);
    STAGEH(0, 1);
    asm volatile("s_waitcnt vmcnt(2)" ::: "memory");
    BARR;

    int t = 0;
    for (; t < NT - 2; ++t) KGROUP(t, "vmcnt(2)");
    for (; t < NT; ++t) KGROUP(t, "vmcnt(0)");

#undef KGROUP
#undef STAGEH
#undef LDA_
#undef LDB_
#undef MM_

    // epilogue: 32x32 C/D layout col=lane&31, row=(reg&3)+8*(reg>>2)+4*(lane>>5)
    // (m74/m101-verified)
    float gam = 0.f;
    if (EPI == 3) gam = *gamma;
    const int rowoff = (l >> 5) << 2;
    const int ncol = l & 31;
#pragma unroll
    for (int af = 0; af < 4; ++af) {
#pragma unroll
        for (int bf = 0; bf < 2; ++bf) {
#pragma unroll
            for (int r = 0; r < 16; ++r) {
                const int m = m0 + wm * 128 + af * 32 + (r & 3) + ((r >> 2) << 3) + rowoff;
                const int n = n0 + wn * 64 + bf * 32 + ncol;
                const float v = acc[af][bf][r];
                const long o = (long)bz * sO + (long)m * Nn + n;
                if (EPI == 0) {
                    ((ushort*)Out)[o] = f2bf(v + bias[n]);
                } else if (EPI == 1) {
                    union { __half h; ushort u; } c;
                    c.h = __float2half(v);
                    ((ushort*)Out)[o] = c.u;
                } else if (EPI == 2) {
                    ((ushort*)Out)[o] = f2bf(v);
                } else if (EPI == 4) {
                    ((ushort*)Out)[o] = f2bf(v + bias[m]);
                } else {
                    const float s = v + bias[n];
                    const float g = 1.f / (1.f + __expf(-s));
                    const float ov = bf2f(outb[(long)m * Nn + n]);
                    ((float*)Out)[o] = gam * ov * g + x1r[(long)m * Nn + n];
                }
            }
        }
    }
}

// ---------------------------------------------------------------------------
// Row softmax IN PLACE: fp16 energy row (2048) -> bf16 attn row (same 4KB)
// ---------------------------------------------------------------------------
__global__ __launch_bounds__(256)
void softmax_inplace(ushort* __restrict__ EA)
{
    const long row = blockIdx.x;
    ushort* p = EA + row * N_;
    const int tid = threadIdx.x;
    const int c0 = tid * 8;
    __shared__ float red[8];

    s16x8 raw = *(const s16x8*)(p + c0);
    float v[8];
    float mx = -3.0e38f;
#pragma unroll
    for (int i = 0; i < 8; ++i) {
        union { ushort u; __half h; } c;
        c.u = (ushort)raw[i];
        v[i] = __half2float(c.h);
        mx = fmaxf(mx, v[i]);
    }
#pragma unroll
    for (int off = 32; off > 0; off >>= 1) mx = fmaxf(mx, __shfl_xor(mx, off));
    if ((tid & 63) == 0) red[tid >> 6] = mx;
    __syncthreads();
    mx = fmaxf(fmaxf(red[0], red[1]), fmaxf(red[2], red[3]));

    float s = 0.f;
#pragma unroll
    for (int i = 0; i < 8; ++i) { v[i] = __expf(v[i] - mx); s += v[i]; }
#pragma unroll
    for (int off = 32; off > 0; off >>= 1) s += __shfl_xor(s, off);
    if ((tid & 63) == 0) red[4 + (tid >> 6)] = s;
    __syncthreads();
    s = (red[4] + red[5]) + (red[6] + red[7]);
    const float inv = 1.f / s;

    s16x8 o;
#pragma unroll
    for (int i = 0; i < 8; ++i) o[i] = (short)f2bf(v[i] * inv);
    *(s16x8*)(p + c0) = o;
}

// ---------------------------------------------------------------------------
extern "C" void kernel_launch(void* const* d_in, const int* in_sizes, int n_in,
                              void* d_out, int out_size, void* d_ws, size_t ws_size,
                              hipStream_t stream)
{
    const float* x1 = (const float*)d_in[0];
    const float* x2 = (const float*)d_in[1];
    const float* Wq = (const float*)d_in[2];
    const float* bq = (const float*)d_in[3];
    const float* Wk = (const float*)d_in[4];
    const float* bk = (const float*)d_in[5];
    const float* Wv = (const float*)d_in[6];
    const float* bv = (const float*)d_in[7];
    const float* W1 = (const float*)d_in[8];
    const float* b1 = (const float*)d_in[9];
    const float* W2 = (const float*)d_in[10];
    const float* b2 = (const float*)d_in[11];
    const float* W3 = (const float*)d_in[12];
    const float* b3 = (const float*)d_in[13];
    const float* gamma = (const float*)d_in[14];
    float* out = (float*)d_out;

    // workspace layout (344 MB peak, with region reuse):
    //   [0]            x1b (67MB) ─┐ after Q/K/Vt GEMMs dead → energy fp16 (134MB) → attn bf16
    //   [67MB]         x2b (67MB) ─┘
    //   [134MB]        wqb, wkb, wvb, wsumb (4 x 2MB), bsum (4KB)
    //   [~142.6MB]     Qb (67MB)
    //   [~209.7MB]     Kb (67MB)  → after energy dead → outb (67MB)
    //   [~276.8MB]     Vt (67MB)  [d][j] layout, computed directly as a GEMM
    char* ws = (char*)d_ws;
    const long SZ_XB = (long)B_ * N_ * D_ * 2;
    ushort* x1b  = (ushort*)(ws);
    ushort* x2b  = (ushort*)(ws + SZ_XB);
    ushort* EA   = (ushort*)(ws);
    ushort* wqb  = (ushort*)(ws + 2 * SZ_XB);
    ushort* wkb  = (ushort*)(ws + 2 * SZ_XB + 1L * 2097152);
    ushort* wvb  = (ushort*)(ws + 2 * SZ_XB + 2L * 2097152);
    ushort* wsb  = (ushort*)(ws + 2 * SZ_XB + 3L * 2097152);
    float*  bsum = (float*) (ws + 2 * SZ_XB + 4L * 2097152);
    char* base2  = ws + 2 * SZ_XB + 4L * 2097152 + 4096;
    ushort* Qb   = (ushort*)(base2);
    ushort* Kb   = (ushort*)(base2 + SZ_XB);
    ushort* Vtb  = (ushort*)(base2 + 2 * SZ_XB);
    ushort* outb = Kb;

    const long NE = (long)B_ * N_ * D_;

    cvt_bf16<<<4096, 256, 0, stream>>>(x1, x1b, NE);
    cvt_bf16<<<4096, 256, 0, stream>>>(x2, x2b, NE);
    prep_w<<<1024, 256, 0, stream>>>(Wq, Wk, Wv, W1, W2, W3, b1, b2, b3,
                                     wqb, wkb, wvb, wsb, bsum);

    // Q = x1 @ Wq^T + bq ; K = x2 @ Wk^T + bk
    gemm256<0><<<dim3(4, 128, 1), 512, 0, stream>>>(x1b, wqb, Qb, bq,
        D_, D_, 16, 0, 0, 0, nullptr, nullptr, nullptr);
    gemm256<0><<<dim3(4, 128, 1), 512, 0, stream>>>(x2b, wkb, Kb, bk,
        D_, D_, 16, 0, 0, 0, nullptr, nullptr, nullptr);

    // Vt[b][d][j] = sum_k Wv[d,k] * x2[b,j,k] + bv[d]  (transpose-free V)
    gemm256<4><<<dim3(8, 4, 16), 512, 0, stream>>>(wvb, x2b, Vtb, bv,
        N_, D_, 16, 0, (long)N_ * D_, (long)D_ * N_,
        nullptr, nullptr, nullptr);

    // energy[b] = Q[b] @ K[b]^T  -> fp16 (over dead x1b/x2b region)
    gemm256<1><<<dim3(8, 8, 16), 512, 0, stream>>>(Qb, Kb, EA, nullptr,
        N_, D_, 16, (long)N_ * D_, (long)N_ * D_, (long)N_ * N_,
        nullptr, nullptr, nullptr);

    // attn = softmax(energy) in place (fp16 row -> bf16 row)
    softmax_inplace<<<B_ * N_, 256, 0, stream>>>(EA);

    // out[b] = attn[b] @ V[b]  (B-operand = Vt, over dead K region)
    gemm256<2><<<dim3(4, 8, 16), 512, 0, stream>>>(EA, Vtb, outb, nullptr,
        D_, N_, 32, (long)N_ * N_, (long)D_ * N_, (long)N_ * D_,
        nullptr, nullptr, nullptr);

    // s = out @ Wsum^T + bsum ; final = gamma * out * sigmoid(s) + x1
    gemm256<3><<<dim3(4, 128, 1), 512, 0, stream>>>(outb, wsb, out, bsum,
        D_, D_, 16, 0, 0, 0, outb, x1, gamma);
}

// Round 6
// 755.612 us; speedup vs baseline: 1.0138x; 1.0138x over previous
//
#include <hip/hip_runtime.h>
#include <hip/hip_bf16.h>
#include <hip/hip_fp16.h>
#include <cstdint>

#define B_ 16
#define N_ 2048
#define D_ 1024

typedef __attribute__((ext_vector_type(4))) float f32x4;
typedef __attribute__((ext_vector_type(8))) short s16x8;

typedef __attribute__((address_space(1))) const void* gas_ptr;
typedef __attribute__((address_space(3))) void* las_ptr;

__device__ __forceinline__ void gload16(const void* g, void* l)
{
    __builtin_amdgcn_global_load_lds((gas_ptr)(uintptr_t)g, (las_ptr)(uintptr_t)l, 16, 0, 0);
}

__device__ __forceinline__ ushort f2bf(float f)
{
    union { __hip_bfloat16 h; ushort u; } c;
    c.h = __float2bfloat16(f);
    return c.u;
}
__device__ __forceinline__ float bf2f(ushort u)
{
    union { __hip_bfloat16 h; ushort u; } c;
    c.u = u;
    return __bfloat162float(c.h);
}

// ---------------------------------------------------------------------------
// fp32 -> bf16 convert (vectorized, grid-stride)
// ---------------------------------------------------------------------------
__global__ __launch_bounds__(256)
void cvt_bf16(const float* __restrict__ in, ushort* __restrict__ out, long n)
{
    long i = ((long)blockIdx.x * 256 + threadIdx.x) * 8;
    const long stride = (long)gridDim.x * 256 * 8;
    for (; i < n; i += stride) {
        f32x4 a = *(const f32x4*)(in + i);
        f32x4 b = *(const f32x4*)(in + i + 4);
        s16x8 o;
#pragma unroll
        for (int j = 0; j < 4; ++j) { o[j] = (short)f2bf(a[j]); o[4 + j] = (short)f2bf(b[j]); }
        *(s16x8*)(out + i) = o;
    }
}

// ---------------------------------------------------------------------------
// weights: bf16 convert + fold W1+W2+W3, b1+b2+b3
// ---------------------------------------------------------------------------
__global__ __launch_bounds__(256)
void prep_w(const float* __restrict__ Wq, const float* __restrict__ Wk, const float* __restrict__ Wv,
            const float* __restrict__ W1, const float* __restrict__ W2, const float* __restrict__ W3,
            const float* __restrict__ b1, const float* __restrict__ b2, const float* __restrict__ b3,
            ushort* __restrict__ wq, ushort* __restrict__ wk, ushort* __restrict__ wv,
            ushort* __restrict__ wsum, float* __restrict__ bsum)
{
    const long i = ((long)blockIdx.x * 256 + threadIdx.x) * 4;
    if (i < (long)D_ * D_) {
#pragma unroll
        for (int j = 0; j < 4; ++j) {
            wq[i + j] = f2bf(Wq[i + j]);
            wk[i + j] = f2bf(Wk[i + j]);
            wv[i + j] = f2bf(Wv[i + j]);
            wsum[i + j] = f2bf(W1[i + j] + W2[i + j] + W3[i + j]);
        }
        if (i < D_) {
#pragma unroll
            for (int j = 0; j < 4; ++j) bsum[i + j] = b1[i + j] + b2[i + j] + b3[i + j];
        }
    }
}

// ---------------------------------------------------------------------------
// 256x256 8-phase bf16 GEMM (m201 template + DEEP counted-vmcnt, WAR-safe):
//   C[m,n] = sum_k A[m,k]*B[n,k] (+epilogue), both operands row-major [rows,K]
//   BK=64, 8 waves (2M x 4N), per-wave 128x64 output (8x4 frags of 16x16x32).
//   LDS 128KB dbuf, st_16x32 swizzle; linear gload_lds dest + inverse-swizzled
//   global source + swizzled ds_read (rule #21).
//   Phases (barriers unchanged from R2 best base):
//     ph0: 12 ds_reads                     | BARR lgkm0 MFMA BARR
//     ph1:  4 ds_reads                     | BARR lgkm0 MFMA BARR
//     ph2:  8 ds_reads + stage B(t+2)      | BARR lgkm0 MFMA BARR
//          (B region of buf t&1 fully consumed at ph1-end barrier)
//     ph3:  stage A(t+2) + MFMA            | vmcnt(8) BARR
//          (A region consumed at ph2-end barrier)
//   Steady-state wait = vmcnt(8): the 8 t+2 loads stay in flight; t+1's
//   halves (issued during t-1, 5-6 phases old) are forced landed. Last two
//   tiles drain vmcnt(0).
// EPI: 0 = +bias[n] -> bf16 | 1 = fp16 | 2 = bf16 | 3 = sigmoid gate -> fp32
//      4 = +bias[m] (row bias) -> bf16
// ---------------------------------------------------------------------------
template<int EPI>
__global__ __launch_bounds__(512, 2)
void gemm256(const ushort* __restrict__ A, const ushort* __restrict__ Bw,
             void* __restrict__ Out, const float* __restrict__ bias,
             int Nn, int K, int NT,
             long sA, long sB, long sO,
             const ushort* __restrict__ outb, const float* __restrict__ x1r,
             const float* __restrict__ gamma)
{
    __shared__ ushort lds[65536];           // 128 KB
    const int tid = threadIdx.x;
    const int l = tid & 63;
    const int w = tid >> 6;
    const int wm = w >> 2, wn = w & 3;
    const int lr = l & 15;
    // swizzled column byte offset for ds_read (bit5 ^= row-bit3 == lr&8), in ushorts
    const int c2x = ((((l >> 4) * 16) ^ ((lr & 8) << 2)) >> 1);

    // bijective XCD-aware block swizzle (all grids are multiples of 8)
    const int gx = gridDim.x, gy = gridDim.y;
    const int nwg = gx * gy * (int)gridDim.z;
    const int orig = ((int)blockIdx.z * gy + blockIdx.y) * gx + blockIdx.x;
    const int swzb = (orig & 7) * (nwg >> 3) + (orig >> 3);
    const int gxy = gx * gy;
    const int bz = swzb / gxy;
    const int rem = swzb - bz * gxy;
    const int by = rem / gx;
    const int bx = rem - by * gx;
    const int m0 = by * 256, n0 = bx * 256;

    const ushort* Ab = A + (long)bz * sA;
    const ushort* Bb = Bw + (long)bz * sB;

    // stage source decode: linear LDS chunk c -> (row, col) via inverse swizzle
    int srow[2], scol[2];
#pragma unroll
    for (int i = 0; i < 2; ++i) {
        const int L = (i * 512 + tid) * 16;
        const int P = L ^ (((L >> 9) & 1) << 5);
        srow[i] = (P >> 6) & 127;
        scol[i] = ((P >> 13) << 5) | ((P & 63) >> 1);
    }
    const int sdst = w * 512;   // wave-uniform LDS chunk base (ushorts), i adds 4096

    f32x4 acc[8][4];
#pragma unroll
    for (int i = 0; i < 8; ++i)
#pragma unroll
        for (int j = 0; j < 4; ++j) acc[i][j] = f32x4{0.f, 0.f, 0.f, 0.f};
    s16x8 a[4][2], b[2][2][2];

#define STAGEH(pl, t)                                                                     \
    if ((t) < NT) {                                                                       \
        const int rb2 = (t) & 1;                                                          \
        const long kk = (long)(t) << 6;                                                   \
        _Pragma("unroll")                                                                 \
        for (int i = 0; i < 2; ++i) {                                                     \
            if ((pl) < 2)                                                                 \
                gload16(Ab + (long)(m0 + (pl) * 128 + srow[i]) * K + kk + scol[i],        \
                        &lds[rb2 * 16384 + (pl) * 8192 + sdst + i * 4096]);               \
            else                                                                          \
                gload16(Bb + (long)(n0 + ((pl) - 2) * 128 + srow[i]) * K + kk + scol[i],  \
                        &lds[32768 + rb2 * 16384 + ((pl) - 2) * 8192 + sdst + i * 4096]); \
        }                                                                                 \
    }

#define LDA_(qm)                                                                           \
    _Pragma("unroll") for (int mi = 0; mi < 4; ++mi)                                       \
    _Pragma("unroll") for (int ks = 0; ks < 2; ++ks)                                       \
        a[mi][ks] = *(const s16x8*)&lds[rbase_a + ks * 4096 + ((qm) * 64 + mi * 16 + lr) * 32 + c2x];

#define LDB_(qn)                                                                           \
    _Pragma("unroll") for (int ni = 0; ni < 2; ++ni)                                       \
    _Pragma("unroll") for (int ks = 0; ks < 2; ++ks)                                       \
        b[qn][ni][ks] = *(const s16x8*)&lds[rbase_b + ks * 4096 +                          \
            ((wn & 1) * 64 + (qn) * 32 + ni * 16 + lr) * 32 + c2x];

#define MM_(qm, qn)                                                                        \
    __builtin_amdgcn_s_setprio(1);                                                         \
    _Pragma("unroll") for (int mi = 0; mi < 4; ++mi)                                       \
    _Pragma("unroll") for (int ni = 0; ni < 2; ++ni)                                       \
    _Pragma("unroll") for (int ks = 0; ks < 2; ++ks)                                       \
        acc[(qm) * 4 + mi][(qn) * 2 + ni] = __builtin_amdgcn_mfma_f32_16x16x32_bf16(       \
            a[mi][ks], b[qn][ni][ks], acc[(qm) * 4 + mi][(qn) * 2 + ni], 0, 0, 0);         \
    __builtin_amdgcn_s_setprio(0);

#define BARR __builtin_amdgcn_s_barrier()
#define LGKM0 do { asm volatile("s_waitcnt lgkmcnt(0)" ::: "memory"); \
                   __builtin_amdgcn_sched_barrier(0); } while (0)

#define KGROUP(tt, VMSTR) {                                          \
    const int rb = (tt) & 1;                                         \
    const int rbase_a = rb * 16384 + wm * 8192;                      \
    const int rbase_b = 32768 + rb * 16384 + (wn >> 1) * 8192;       \
    /* ph0 */                                                        \
    LDB_(0); LDA_(0);                                                \
    BARR; LGKM0; MM_(0, 0); BARR;                                    \
    /* ph1 */                                                        \
    LDB_(1);                                                         \
    BARR; LGKM0; MM_(0, 1); BARR;                                    \
    /* ph2: B region of buf rb consumed (ph1-end) -> stage B(t+2) */ \
    LDA_(1);                                                         \
    STAGEH(2, (tt) + 2);                                             \
    STAGEH(3, (tt) + 2);                                             \
    BARR; LGKM0; MM_(1, 0); BARR;                                    \
    /* ph3: A region consumed (ph2-end) -> stage A(t+2) */           \
    STAGEH(0, (tt) + 2);                                             \
    STAGEH(1, (tt) + 2);                                             \
    MM_(1, 1);                                                       \
    asm volatile("s_waitcnt " VMSTR ::: "memory");                   \
    BARR; }

    // prologue: tiles 0 and 1 fully staged; wait tile0 (tile1's 8 stay in flight)
    STAGEH(0, 0); STAGEH(1, 0); STAGEH(2, 0); STAGEH(3, 0);
    STAGEH(0, 1); STAGEH(1, 1); STAGEH(2, 1); STAGEH(3, 1);
    asm volatile("s_waitcnt vmcnt(8)" ::: "memory");
    BARR;

    int t = 0;
    for (; t < NT - 2; ++t) KGROUP(t, "vmcnt(8)");
    for (; t < NT; ++t) KGROUP(t, "vmcnt(0)");

#undef KGROUP
#undef STAGEH
#undef LDA_
#undef LDB_
#undef MM_

    // epilogue: C/D layout col=lane&15, row=(lane>>4)*4+reg (m89-verified)
    float gam = 0.f;
    if (EPI == 3) gam = *gamma;
#pragma unroll
    for (int am = 0; am < 8; ++am) {
#pragma unroll
        for (int an = 0; an < 4; ++an) {
#pragma unroll
            for (int r = 0; r < 4; ++r) {
                const int m = m0 + wm * 128 + am * 16 + (l >> 4) * 4 + r;
                const int n = n0 + wn * 64 + an * 16 + lr;
                const float v = acc[am][an][r];
                const long o = (long)bz * sO + (long)m * Nn + n;
                if (EPI == 0) {
                    ((ushort*)Out)[o] = f2bf(v + bias[n]);
                } else if (EPI == 1) {
                    union { __half h; ushort u; } c;
                    c.h = __float2half(v);
                    ((ushort*)Out)[o] = c.u;
                } else if (EPI == 2) {
                    ((ushort*)Out)[o] = f2bf(v);
                } else if (EPI == 4) {
                    ((ushort*)Out)[o] = f2bf(v + bias[m]);
                } else {
                    const float s = v + bias[n];
                    const float g = 1.f / (1.f + __expf(-s));
                    const float ov = bf2f(outb[(long)m * Nn + n]);
                    ((float*)Out)[o] = gam * ov * g + x1r[(long)m * Nn + n];
                }
            }
        }
    }
}

// ---------------------------------------------------------------------------
// Row softmax IN PLACE: fp16 energy row (2048) -> bf16 attn row (same 4KB)
// ---------------------------------------------------------------------------
__global__ __launch_bounds__(256)
void softmax_inplace(ushort* __restrict__ EA)
{
    const long row = blockIdx.x;
    ushort* p = EA + row * N_;
    const int tid = threadIdx.x;
    const int c0 = tid * 8;
    __shared__ float red[8];

    s16x8 raw = *(const s16x8*)(p + c0);
    float v[8];
    float mx = -3.0e38f;
#pragma unroll
    for (int i = 0; i < 8; ++i) {
        union { ushort u; __half h; } c;
        c.u = (ushort)raw[i];
        v[i] = __half2float(c.h);
        mx = fmaxf(mx, v[i]);
    }
#pragma unroll
    for (int off = 32; off > 0; off >>= 1) mx = fmaxf(mx, __shfl_xor(mx, off));
    if ((tid & 63) == 0) red[tid >> 6] = mx;
    __syncthreads();
    mx = fmaxf(fmaxf(red[0], red[1]), fmaxf(red[2], red[3]));

    float s = 0.f;
#pragma unroll
    for (int i = 0; i < 8; ++i) { v[i] = __expf(v[i] - mx); s += v[i]; }
#pragma unroll
    for (int off = 32; off > 0; off >>= 1) s += __shfl_xor(s, off);
    if ((tid & 63) == 0) red[4 + (tid >> 6)] = s;
    __syncthreads();
    s = (red[4] + red[5]) + (red[6] + red[7]);
    const float inv = 1.f / s;

    s16x8 o;
#pragma unroll
    for (int i = 0; i < 8; ++i) o[i] = (short)f2bf(v[i] * inv);
    *(s16x8*)(p + c0) = o;
}

// ---------------------------------------------------------------------------
extern "C" void kernel_launch(void* const* d_in, const int* in_sizes, int n_in,
                              void* d_out, int out_size, void* d_ws, size_t ws_size,
                              hipStream_t stream)
{
    const float* x1 = (const float*)d_in[0];
    const float* x2 = (const float*)d_in[1];
    const float* Wq = (const float*)d_in[2];
    const float* bq = (const float*)d_in[3];
    const float* Wk = (const float*)d_in[4];
    const float* bk = (const float*)d_in[5];
    const float* Wv = (const float*)d_in[6];
    const float* bv = (const float*)d_in[7];
    const float* W1 = (const float*)d_in[8];
    const float* b1 = (const float*)d_in[9];
    const float* W2 = (const float*)d_in[10];
    const float* b2 = (const float*)d_in[11];
    const float* W3 = (const float*)d_in[12];
    const float* b3 = (const float*)d_in[13];
    const float* gamma = (const float*)d_in[14];
    float* out = (float*)d_out;

    // workspace layout (344 MB peak, with region reuse):
    //   [0]            x1b (67MB) ─┐ after Q/K/Vt GEMMs dead → energy fp16 (134MB) → attn bf16
    //   [67MB]         x2b (67MB) ─┘
    //   [134MB]        wqb, wkb, wvb, wsumb (4 x 2MB), bsum (4KB)
    //   [~142.6MB]     Qb (67MB)
    //   [~209.7MB]     Kb (67MB)  → after energy dead → outb (67MB)
    //   [~276.8MB]     Vt (67MB)  [d][j] layout, computed directly as a GEMM
    char* ws = (char*)d_ws;
    const long SZ_XB = (long)B_ * N_ * D_ * 2;
    ushort* x1b  = (ushort*)(ws);
    ushort* x2b  = (ushort*)(ws + SZ_XB);
    ushort* EA   = (ushort*)(ws);
    ushort* wqb  = (ushort*)(ws + 2 * SZ_XB);
    ushort* wkb  = (ushort*)(ws + 2 * SZ_XB + 1L * 2097152);
    ushort* wvb  = (ushort*)(ws + 2 * SZ_XB + 2L * 2097152);
    ushort* wsb  = (ushort*)(ws + 2 * SZ_XB + 3L * 2097152);
    float*  bsum = (float*) (ws + 2 * SZ_XB + 4L * 2097152);
    char* base2  = ws + 2 * SZ_XB + 4L * 2097152 + 4096;
    ushort* Qb   = (ushort*)(base2);
    ushort* Kb   = (ushort*)(base2 + SZ_XB);
    ushort* Vtb  = (ushort*)(base2 + 2 * SZ_XB);
    ushort* outb = Kb;

    const long NE = (long)B_ * N_ * D_;

    cvt_bf16<<<4096, 256, 0, stream>>>(x1, x1b, NE);
    cvt_bf16<<<4096, 256, 0, stream>>>(x2, x2b, NE);
    prep_w<<<1024, 256, 0, stream>>>(Wq, Wk, Wv, W1, W2, W3, b1, b2, b3,
                                     wqb, wkb, wvb, wsb, bsum);

    // Q = x1 @ Wq^T + bq ; K = x2 @ Wk^T + bk
    gemm256<0><<<dim3(4, 128, 1), 512, 0, stream>>>(x1b, wqb, Qb, bq,
        D_, D_, 16, 0, 0, 0, nullptr, nullptr, nullptr);
    gemm256<0><<<dim3(4, 128, 1), 512, 0, stream>>>(x2b, wkb, Kb, bk,
        D_, D_, 16, 0, 0, 0, nullptr, nullptr, nullptr);

    // Vt[b][d][j] = sum_k Wv[d,k] * x2[b,j,k] + bv[d]  (transpose-free V)
    gemm256<4><<<dim3(8, 4, 16), 512, 0, stream>>>(wvb, x2b, Vtb, bv,
        N_, D_, 16, 0, (long)N_ * D_, (long)D_ * N_,
        nullptr, nullptr, nullptr);

    // energy[b] = Q[b] @ K[b]^T  -> fp16 (over dead x1b/x2b region)
    gemm256<1><<<dim3(8, 8, 16), 512, 0, stream>>>(Qb, Kb, EA, nullptr,
        N_, D_, 16, (long)N_ * D_, (long)N_ * D_, (long)N_ * N_,
        nullptr, nullptr, nullptr);

    // attn = softmax(energy) in place (fp16 row -> bf16 row)
    softmax_inplace<<<B_ * N_, 256, 0, stream>>>(EA);

    // out[b] = attn[b] @ V[b]  (B-operand = Vt, over dead K region)
    gemm256<2><<<dim3(4, 8, 16), 512, 0, stream>>>(EA, Vtb, outb, nullptr,
        D_, N_, 32, (long)N_ * N_, (long)D_ * N_, (long)N_ * D_,
        nullptr, nullptr, nullptr);

    // s = out @ Wsum^T + bsum ; final = gamma * out * sigmoid(s) + x1
    gemm256<3><<<dim3(4, 128, 1), 512, 0, stream>>>(outb, wsb, out, bsum,
        D_, D_, 16, 0, 0, 0, outb, x1, gamma);
}

// Round 7
// 728.714 us; speedup vs baseline: 1.0512x; 1.0369x over previous
//
#include <hip/hip_runtime.h>
#include <hip/hip_bf16.h>
#include <hip/hip_fp16.h>
#include <cstdint>

#define B_ 16
#define N_ 2048
#define D_ 1024

typedef __attribute__((ext_vector_type(4))) float f32x4;
typedef __attribute__((ext_vector_type(8))) short s16x8;

typedef __attribute__((address_space(1))) const void* gas_ptr;
typedef __attribute__((address_space(3))) void* las_ptr;

__device__ __forceinline__ void gload16(const void* g, void* l)
{
    __builtin_amdgcn_global_load_lds((gas_ptr)(uintptr_t)g, (las_ptr)(uintptr_t)l, 16, 0, 0);
}

__device__ __forceinline__ ushort f2bf(float f)
{
    union { __hip_bfloat16 h; ushort u; } c;
    c.h = __float2bfloat16(f);
    return c.u;
}
__device__ __forceinline__ float bf2f(ushort u)
{
    union { __hip_bfloat16 h; ushort u; } c;
    c.u = u;
    return __bfloat162float(c.h);
}

// ---------------------------------------------------------------------------
// fp32 -> bf16 convert (vectorized, grid-stride)
// ---------------------------------------------------------------------------
__global__ __launch_bounds__(256)
void cvt_bf16(const float* __restrict__ in, ushort* __restrict__ out, long n)
{
    long i = ((long)blockIdx.x * 256 + threadIdx.x) * 8;
    const long stride = (long)gridDim.x * 256 * 8;
    for (; i < n; i += stride) {
        f32x4 a = *(const f32x4*)(in + i);
        f32x4 b = *(const f32x4*)(in + i + 4);
        s16x8 o;
#pragma unroll
        for (int j = 0; j < 4; ++j) { o[j] = (short)f2bf(a[j]); o[4 + j] = (short)f2bf(b[j]); }
        *(s16x8*)(out + i) = o;
    }
}

// ---------------------------------------------------------------------------
// weights: bf16 convert + fold W1+W2+W3, b1+b2+b3
// ---------------------------------------------------------------------------
__global__ __launch_bounds__(256)
void prep_w(const float* __restrict__ Wq, const float* __restrict__ Wk, const float* __restrict__ Wv,
            const float* __restrict__ W1, const float* __restrict__ W2, const float* __restrict__ W3,
            const float* __restrict__ b1, const float* __restrict__ b2, const float* __restrict__ b3,
            ushort* __restrict__ wq, ushort* __restrict__ wk, ushort* __restrict__ wv,
            ushort* __restrict__ wsum, float* __restrict__ bsum)
{
    const long i = ((long)blockIdx.x * 256 + threadIdx.x) * 4;
    if (i < (long)D_ * D_) {
#pragma unroll
        for (int j = 0; j < 4; ++j) {
            wq[i + j] = f2bf(Wq[i + j]);
            wk[i + j] = f2bf(Wk[i + j]);
            wv[i + j] = f2bf(Wv[i + j]);
            wsum[i + j] = f2bf(W1[i + j] + W2[i + j] + W3[i + j]);
        }
        if (i < D_) {
#pragma unroll
            for (int j = 0; j < 4; ++j) bsum[i + j] = b1[i + j] + b2[i + j] + b3[i + j];
        }
    }
}

// ---------------------------------------------------------------------------
// 256x256 8-phase bf16 GEMM (m201 template, compiler-scheduled interior):
//   C[m,n] = sum_k A[m,k]*B[n,k] (+epilogue), both operands row-major [rows,K]
//   BK=64, 8 waves (2M x 4N), per-wave 128x64 output (8x4 frags of 16x16x32).
//   LDS 128KB dbuf, st_16x32 swizzle; linear gload_lds dest + inverse-swizzled
//   global source + swizzled ds_read (rule #21).
//   R1 stage rotation (best measured): halves 1-3 of t+1 staged at ph0-2,
//   half 0 of t+2 at ph3; vmcnt(2) at tile end, vmcnt(0) for last two tiles.
//   NO explicit lgkmcnt(0)/sched_barrier before MFMA clusters: ds_reads are
//   plain C++ loads, the compiler emits fine-grained lgkmcnt(N) so early
//   MFMAs overlap tail ds_reads (m97/m141 evidence; the hard drain+pin was
//   the 5-null culprit).
// EPI: 0 = +bias[n] -> bf16 | 1 = fp16 | 2 = bf16 | 3 = sigmoid gate -> fp32
//      4 = +bias[m] (row bias) -> bf16
// ---------------------------------------------------------------------------
template<int EPI>
__global__ __launch_bounds__(512, 2)
void gemm256(const ushort* __restrict__ A, const ushort* __restrict__ Bw,
             void* __restrict__ Out, const float* __restrict__ bias,
             int Nn, int K, int NT,
             long sA, long sB, long sO,
             const ushort* __restrict__ outb, const float* __restrict__ x1r,
             const float* __restrict__ gamma)
{
    __shared__ ushort lds[65536];           // 128 KB
    const int tid = threadIdx.x;
    const int l = tid & 63;
    const int w = tid >> 6;
    const int wm = w >> 2, wn = w & 3;
    const int lr = l & 15;
    // swizzled column byte offset for ds_read (bit5 ^= row-bit3 == lr&8), in ushorts
    const int c2x = ((((l >> 4) * 16) ^ ((lr & 8) << 2)) >> 1);

    // bijective XCD-aware block swizzle (all grids are multiples of 8)
    const int gx = gridDim.x, gy = gridDim.y;
    const int nwg = gx * gy * (int)gridDim.z;
    const int orig = ((int)blockIdx.z * gy + blockIdx.y) * gx + blockIdx.x;
    const int swzb = (orig & 7) * (nwg >> 3) + (orig >> 3);
    const int gxy = gx * gy;
    const int bz = swzb / gxy;
    const int rem = swzb - bz * gxy;
    const int by = rem / gx;
    const int bx = rem - by * gx;
    const int m0 = by * 256, n0 = bx * 256;

    const ushort* Ab = A + (long)bz * sA;
    const ushort* Bb = Bw + (long)bz * sB;

    // stage source decode: linear LDS chunk c -> (row, col) via inverse swizzle
    int srow[2], scol[2];
#pragma unroll
    for (int i = 0; i < 2; ++i) {
        const int L = (i * 512 + tid) * 16;
        const int P = L ^ (((L >> 9) & 1) << 5);
        srow[i] = (P >> 6) & 127;
        scol[i] = ((P >> 13) << 5) | ((P & 63) >> 1);
    }
    const int sdst = w * 512;   // wave-uniform LDS chunk base (ushorts), i adds 4096

    f32x4 acc[8][4];
#pragma unroll
    for (int i = 0; i < 8; ++i)
#pragma unroll
        for (int j = 0; j < 4; ++j) acc[i][j] = f32x4{0.f, 0.f, 0.f, 0.f};
    s16x8 a[4][2], b[2][2][2];

#define STAGEH(pl, t)                                                                     \
    if ((t) < NT) {                                                                       \
        const int rb2 = (t) & 1;                                                          \
        const long kk = (long)(t) << 6;                                                   \
        _Pragma("unroll")                                                                 \
        for (int i = 0; i < 2; ++i) {                                                     \
            if ((pl) < 2)                                                                 \
                gload16(Ab + (long)(m0 + (pl) * 128 + srow[i]) * K + kk + scol[i],        \
                        &lds[rb2 * 16384 + (pl) * 8192 + sdst + i * 4096]);               \
            else                                                                          \
                gload16(Bb + (long)(n0 + ((pl) - 2) * 128 + srow[i]) * K + kk + scol[i],  \
                        &lds[32768 + rb2 * 16384 + ((pl) - 2) * 8192 + sdst + i * 4096]); \
        }                                                                                 \
    }

#define LDA_(qm)                                                                           \
    _Pragma("unroll") for (int mi = 0; mi < 4; ++mi)                                       \
    _Pragma("unroll") for (int ks = 0; ks < 2; ++ks)                                       \
        a[mi][ks] = *(const s16x8*)&lds[rbase_a + ks * 4096 + ((qm) * 64 + mi * 16 + lr) * 32 + c2x];

#define LDB_(qn)                                                                           \
    _Pragma("unroll") for (int ni = 0; ni < 2; ++ni)                                       \
    _Pragma("unroll") for (int ks = 0; ks < 2; ++ks)                                       \
        b[qn][ni][ks] = *(const s16x8*)&lds[rbase_b + ks * 4096 +                          \
            ((wn & 1) * 64 + (qn) * 32 + ni * 16 + lr) * 32 + c2x];

#define MM_(qm, qn)                                                                        \
    __builtin_amdgcn_s_setprio(1);                                                         \
    _Pragma("unroll") for (int mi = 0; mi < 4; ++mi)                                       \
    _Pragma("unroll") for (int ni = 0; ni < 2; ++ni)                                       \
    _Pragma("unroll") for (int ks = 0; ks < 2; ++ks)                                       \
        acc[(qm) * 4 + mi][(qn) * 2 + ni] = __builtin_amdgcn_mfma_f32_16x16x32_bf16(       \
            a[mi][ks], b[qn][ni][ks], acc[(qm) * 4 + mi][(qn) * 2 + ni], 0, 0, 0);         \
    __builtin_amdgcn_s_setprio(0);

#define BARR __builtin_amdgcn_s_barrier()

#define KGROUP(tt, VMSTR) {                                          \
    const int rb = (tt) & 1;                                         \
    const int rbase_a = rb * 16384 + wm * 8192;                      \
    const int rbase_b = 32768 + rb * 16384 + (wn >> 1) * 8192;       \
    /* ph0 */                                                        \
    LDB_(0); LDA_(0);                                                \
    STAGEH(1, (tt) + 1);                                             \
    BARR; MM_(0, 0); BARR;                                           \
    /* ph1 */                                                        \
    LDB_(1);                                                         \
    STAGEH(2, (tt) + 1);                                             \
    BARR; MM_(0, 1); BARR;                                           \
    /* ph2 */                                                        \
    LDA_(1);                                                         \
    STAGEH(3, (tt) + 1);                                             \
    BARR; MM_(1, 0); BARR;                                           \
    /* ph3: full frag reuse; stage next-next tile's A-half0 after MFMA */ \
    MM_(1, 1);                                                       \
    STAGEH(0, (tt) + 2);                                             \
    asm volatile("s_waitcnt " VMSTR ::: "memory");                   \
    BARR; }

    // prologue: tile0 fully + half0 of tile1 in flight
    STAGEH(0, 0); STAGEH(1, 0); STAGEH(2, 0); STAGEH(3, 0);
    STAGEH(0, 1);
    asm volatile("s_waitcnt vmcnt(2)" ::: "memory");
    BARR;

    int t = 0;
    for (; t < NT - 2; ++t) KGROUP(t, "vmcnt(2)");
    for (; t < NT; ++t) KGROUP(t, "vmcnt(0)");

#undef KGROUP
#undef STAGEH
#undef LDA_
#undef LDB_
#undef MM_

    // epilogue: C/D layout col=lane&15, row=(lane>>4)*4+reg (m89-verified)
    float gam = 0.f;
    if (EPI == 3) gam = *gamma;
#pragma unroll
    for (int am = 0; am < 8; ++am) {
#pragma unroll
        for (int an = 0; an < 4; ++an) {
#pragma unroll
            for (int r = 0; r < 4; ++r) {
                const int m = m0 + wm * 128 + am * 16 + (l >> 4) * 4 + r;
                const int n = n0 + wn * 64 + an * 16 + lr;
                const float v = acc[am][an][r];
                const long o = (long)bz * sO + (long)m * Nn + n;
                if (EPI == 0) {
                    ((ushort*)Out)[o] = f2bf(v + bias[n]);
                } else if (EPI == 1) {
                    union { __half h; ushort u; } c;
                    c.h = __float2half(v);
                    ((ushort*)Out)[o] = c.u;
                } else if (EPI == 2) {
                    ((ushort*)Out)[o] = f2bf(v);
                } else if (EPI == 4) {
                    ((ushort*)Out)[o] = f2bf(v + bias[m]);
                } else {
                    const float s = v + bias[n];
                    const float g = 1.f / (1.f + __expf(-s));
                    const float ov = bf2f(outb[(long)m * Nn + n]);
                    ((float*)Out)[o] = gam * ov * g + x1r[(long)m * Nn + n];
                }
            }
        }
    }
}

// ---------------------------------------------------------------------------
// Row softmax IN PLACE: fp16 energy row (2048) -> bf16 attn row (same 4KB)
// ---------------------------------------------------------------------------
__global__ __launch_bounds__(256)
void softmax_inplace(ushort* __restrict__ EA)
{
    const long row = blockIdx.x;
    ushort* p = EA + row * N_;
    const int tid = threadIdx.x;
    const int c0 = tid * 8;
    __shared__ float red[8];

    s16x8 raw = *(const s16x8*)(p + c0);
    float v[8];
    float mx = -3.0e38f;
#pragma unroll
    for (int i = 0; i < 8; ++i) {
        union { ushort u; __half h; } c;
        c.u = (ushort)raw[i];
        v[i] = __half2float(c.h);
        mx = fmaxf(mx, v[i]);
    }
#pragma unroll
    for (int off = 32; off > 0; off >>= 1) mx = fmaxf(mx, __shfl_xor(mx, off));
    if ((tid & 63) == 0) red[tid >> 6] = mx;
    __syncthreads();
    mx = fmaxf(fmaxf(red[0], red[1]), fmaxf(red[2], red[3]));

    float s = 0.f;
#pragma unroll
    for (int i = 0; i < 8; ++i) { v[i] = __expf(v[i] - mx); s += v[i]; }
#pragma unroll
    for (int off = 32; off > 0; off >>= 1) s += __shfl_xor(s, off);
    if ((tid & 63) == 0) red[4 + (tid >> 6)] = s;
    __syncthreads();
    s = (red[4] + red[5]) + (red[6] + red[7]);
    const float inv = 1.f / s;

    s16x8 o;
#pragma unroll
    for (int i = 0; i < 8; ++i) o[i] = (short)f2bf(v[i] * inv);
    *(s16x8*)(p + c0) = o;
}

// ---------------------------------------------------------------------------
extern "C" void kernel_launch(void* const* d_in, const int* in_sizes, int n_in,
                              void* d_out, int out_size, void* d_ws, size_t ws_size,
                              hipStream_t stream)
{
    const float* x1 = (const float*)d_in[0];
    const float* x2 = (const float*)d_in[1];
    const float* Wq = (const float*)d_in[2];
    const float* bq = (const float*)d_in[3];
    const float* Wk = (const float*)d_in[4];
    const float* bk = (const float*)d_in[5];
    const float* Wv = (const float*)d_in[6];
    const float* bv = (const float*)d_in[7];
    const float* W1 = (const float*)d_in[8];
    const float* b1 = (const float*)d_in[9];
    const float* W2 = (const float*)d_in[10];
    const float* b2 = (const float*)d_in[11];
    const float* W3 = (const float*)d_in[12];
    const float* b3 = (const float*)d_in[13];
    const float* gamma = (const float*)d_in[14];
    float* out = (float*)d_out;

    // workspace layout (344 MB peak, with region reuse):
    //   [0]            x1b (67MB) ─┐ after Q/K/Vt GEMMs dead → energy fp16 (134MB) → attn bf16
    //   [67MB]         x2b (67MB) ─┘
    //   [134MB]        wqb, wkb, wvb, wsumb (4 x 2MB), bsum (4KB)
    //   [~142.6MB]     Qb (67MB)
    //   [~209.7MB]     Kb (67MB)  → after energy dead → outb (67MB)
    //   [~276.8MB]     Vt (67MB)  [d][j] layout, computed directly as a GEMM
    char* ws = (char*)d_ws;
    const long SZ_XB = (long)B_ * N_ * D_ * 2;
    ushort* x1b  = (ushort*)(ws);
    ushort* x2b  = (ushort*)(ws + SZ_XB);
    ushort* EA   = (ushort*)(ws);
    ushort* wqb  = (ushort*)(ws + 2 * SZ_XB);
    ushort* wkb  = (ushort*)(ws + 2 * SZ_XB + 1L * 2097152);
    ushort* wvb  = (ushort*)(ws + 2 * SZ_XB + 2L * 2097152);
    ushort* wsb  = (ushort*)(ws + 2 * SZ_XB + 3L * 2097152);
    float*  bsum = (float*) (ws + 2 * SZ_XB + 4L * 2097152);
    char* base2  = ws + 2 * SZ_XB + 4L * 2097152 + 4096;
    ushort* Qb   = (ushort*)(base2);
    ushort* Kb   = (ushort*)(base2 + SZ_XB);
    ushort* Vtb  = (ushort*)(base2 + 2 * SZ_XB);
    ushort* outb = Kb;

    const long NE = (long)B_ * N_ * D_;

    cvt_bf16<<<4096, 256, 0, stream>>>(x1, x1b, NE);
    cvt_bf16<<<4096, 256, 0, stream>>>(x2, x2b, NE);
    prep_w<<<1024, 256, 0, stream>>>(Wq, Wk, Wv, W1, W2, W3, b1, b2, b3,
                                     wqb, wkb, wvb, wsb, bsum);

    // Q = x1 @ Wq^T + bq ; K = x2 @ Wk^T + bk
    gemm256<0><<<dim3(4, 128, 1), 512, 0, stream>>>(x1b, wqb, Qb, bq,
        D_, D_, 16, 0, 0, 0, nullptr, nullptr, nullptr);
    gemm256<0><<<dim3(4, 128, 1), 512, 0, stream>>>(x2b, wkb, Kb, bk,
        D_, D_, 16, 0, 0, 0, nullptr, nullptr, nullptr);

    // Vt[b][d][j] = sum_k Wv[d,k] * x2[b,j,k] + bv[d]  (transpose-free V)
    gemm256<4><<<dim3(8, 4, 16), 512, 0, stream>>>(wvb, x2b, Vtb, bv,
        N_, D_, 16, 0, (long)N_ * D_, (long)D_ * N_,
        nullptr, nullptr, nullptr);

    // energy[b] = Q[b] @ K[b]^T  -> fp16 (over dead x1b/x2b region)
    gemm256<1><<<dim3(8, 8, 16), 512, 0, stream>>>(Qb, Kb, EA, nullptr,
        N_, D_, 16, (long)N_ * D_, (long)N_ * D_, (long)N_ * N_,
        nullptr, nullptr, nullptr);

    // attn = softmax(energy) in place (fp16 row -> bf16 row)
    softmax_inplace<<<B_ * N_, 256, 0, stream>>>(EA);

    // out[b] = attn[b] @ V[b]  (B-operand = Vt, over dead K region)
    gemm256<2><<<dim3(4, 8, 16), 512, 0, stream>>>(EA, Vtb, outb, nullptr,
        D_, N_, 32, (long)N_ * N_, (long)D_ * N_, (long)N_ * D_,
        nullptr, nullptr, nullptr);

    // s = out @ Wsum^T + bsum ; final = gamma * out * sigmoid(s) + x1
    gemm256<3><<<dim3(4, 128, 1), 512, 0, stream>>>(outb, wsb, out, bsum,
        D_, D_, 16, 0, 0, 0, outb, x1, gamma);
}